// Round 1
// baseline (139.160 us; speedup 1.0000x reference)
//
#include <hip/hip_runtime.h>
#include <math.h>

// Problem constants (from reference setup_inputs)
#define NQ 2048
#define NB 8192
#define DIM 32

// Tiling
#define TPB 256                 // threads per block
#define BPT 2                   // backgrounds per thread (adjacent -> float2 r loads)
#define BG_PER_BLOCK (TPB * BPT) // 512
#define QTILE 32                // queries per block

#define LOG2E 1.44269504088896340736f

// grid = (NB/BG_PER_BLOCK = 16, NQ/QTILE = 64) = 1024 blocks, 4 waves each
__global__ __launch_bounds__(TPB) void relnw_partial(
    const float* __restrict__ xb,     // (NB, DIM)
    const float* __restrict__ yb,     // (NB,)
    const float* __restrict__ xq,     // (NQ, DIM)
    const float* __restrict__ r,      // (NQ, NB)
    const float* __restrict__ sigma,  // (1,)
    const float* __restrict__ rscale, // (1,)
    const float* __restrict__ w,      // (DIM,)
    float* __restrict__ acc)          // ws: [0:NQ] = sum_k, [NQ:2NQ] = sum_ky
{
    __shared__ float sq2[QTILE];

    const int tid = threadIdx.x;
    const int b0  = blockIdx.x * BG_PER_BLOCK + tid * BPT;
    const int q0  = blockIdx.y * QTILE;

    const float c1 = -LOG2E / sigma[0];      // coeff on dist (log2 space)
    const float c2 =  LOG2E * rscale[0];     // coeff on r    (log2 space)

    // Load this thread's backgrounds: xb2w[d] = xb[d]*w[d]^2 (w^2 folded into
    // background side so the query row can be used raw from SGPRs).
    float xb2w[BPT][DIM];
    float b2[BPT], yv[BPT];
#pragma unroll
    for (int j = 0; j < BPT; ++j) {
        const float* row = xb + (size_t)(b0 + j) * DIM;
        float s = 0.f;
#pragma unroll
        for (int d = 0; d < DIM; ++d) {
            float wv = w[d];              // uniform -> s_load
            float t  = row[d] * wv;       // (xb*w)
            s        = fmaf(t, t, s);     // b2 = sum (xb*w)^2
            xb2w[j][d] = t * wv;          // xb*w^2
        }
        b2[j] = s;
        yv[j] = yb[b0 + j];
    }

    // q2 for this block's query tile: q2 = sum (xq*w)^2
    if (tid < QTILE) {
        const float* row = xq + (size_t)(q0 + tid) * DIM;
        float s = 0.f;
#pragma unroll
        for (int d = 0; d < DIM; ++d) {
            float t = row[d] * w[d];
            s = fmaf(t, t, s);
        }
        sq2[tid] = s;
    }
    __syncthreads();

    for (int qi = 0; qi < QTILE; ++qi) {
        const int q = q0 + qi;
        const float* xqr = xq + (size_t)q * DIM;  // wave-uniform -> s_load row

        // r for this thread's 2 backgrounds: coalesced float2
        const float2 rv = *(const float2*)(r + (size_t)q * NB + b0);
        const float q2 = sq2[qi];

        float sk = 0.f, sky = 0.f;
#pragma unroll
        for (int j = 0; j < BPT; ++j) {
            float dot = 0.f;
#pragma unroll
            for (int d = 0; d < DIM; ++d)
                dot = fmaf(xqr[d], xb2w[j][d], dot);   // v_fmac v,s,v
            float d2 = fmaf(-2.f, dot, q2 + b2[j]);
            d2 = fmaxf(d2, 0.f);
            float dist = __builtin_amdgcn_sqrtf(d2);
            float rj = (j == 0) ? rv.x : rv.y;
            float e = fmaf(dist, c1, rj * c2);         // log2-space exponent
            float k = __builtin_amdgcn_exp2f(e);
            sk += k;
            sky = fmaf(k, yv[j], sky);
        }

        // 64-lane butterfly reduction
#pragma unroll
        for (int off = 32; off > 0; off >>= 1) {
            sk  += __shfl_xor(sk,  off, 64);
            sky += __shfl_xor(sky, off, 64);
        }
        if ((tid & 63) == 0) {
            atomicAdd(acc + q,      sk);
            atomicAdd(acc + NQ + q, sky);
        }
    }
}

__global__ __launch_bounds__(256) void relnw_finalize(
    const float* __restrict__ acc, float* __restrict__ out)
{
    int q = blockIdx.x * 256 + threadIdx.x;
    if (q < NQ)
        out[q] = acc[NQ + q] / (acc[q] + 1e-8f);
}

extern "C" void kernel_launch(void* const* d_in, const int* in_sizes, int n_in,
                              void* d_out, int out_size, void* d_ws, size_t ws_size,
                              hipStream_t stream) {
    const float* xb     = (const float*)d_in[0]; // (8192,32)
    const float* yb     = (const float*)d_in[1]; // (8192,)
    const float* xq     = (const float*)d_in[2]; // (2048,32)
    const float* r      = (const float*)d_in[3]; // (2048,8192)
    const float* sigma  = (const float*)d_in[4]; // (1,)
    const float* rscale = (const float*)d_in[5]; // (1,)
    const float* w      = (const float*)d_in[6]; // (32,)
    float* out = (float*)d_out;
    float* acc = (float*)d_ws;                   // 2*NQ floats = 16 KB

    // ws is poisoned 0xAA before every timed launch -> zero the accumulators
    hipMemsetAsync(acc, 0, 2 * NQ * sizeof(float), stream);

    dim3 grid(NB / BG_PER_BLOCK, NQ / QTILE);    // (16, 64)
    relnw_partial<<<grid, TPB, 0, stream>>>(xb, yb, xq, r, sigma, rscale, w, acc);
    relnw_finalize<<<(NQ + 255) / 256, 256, 0, stream>>>(acc, out);
}